// Round 7
// baseline (162.570 us; speedup 1.0000x reference)
//
#include <hip/hip_runtime.h>
#include <math.h>

#define NROWS 32768
#define NCODE 1024
#define GAP_THRESH 1.5e-4f  // exact fp32 gap; emulation err ~1e-5, np-ref rounding ~2e-5
#define AMB_MAX 16          // per-block ambiguous-row cap (expected 0.06/block)

typedef __attribute__((ext_vector_type(8))) short bf16x8;   // 8 bf16 = 4 VGPRs
typedef __attribute__((ext_vector_type(4))) float f32x4;    // MFMA acc

__device__ __forceinline__ unsigned short bf16_rne(float f) {
    unsigned u = __float_as_uint(f);
    unsigned r = u + 0x7FFFu + ((u >> 16) & 1u);
    return (unsigned short)(r >> 16);
}

typedef const __attribute__((address_space(1))) unsigned GU;
typedef __attribute__((address_space(3))) unsigned LU;
__device__ __forceinline__ void gl_lds16(const void* g, void* l) {
    __builtin_amdgcn_global_load_lds((GU*)g, (LU*)l, 16, 0, 0);
}
__device__ __forceinline__ void gl_lds4(const void* g, void* l) {
    __builtin_amdgcn_global_load_lds((GU*)g, (LU*)l, 4, 0, 0);
}

// ---------------------------------------------------------------------------
// prep: cn4 = ||c||^2+4, zero gsumsq/ticket, codebook -> frag-major split-bf16.
// ---------------------------------------------------------------------------
__global__ __launch_bounds__(256) void vq_prep(
    const float* __restrict__ cb, float* __restrict__ cn4,
    float* __restrict__ gsumsq, unsigned* __restrict__ ticket,
    unsigned short* __restrict__ wsB)
{
    int c = blockIdx.x * 256 + threadIdx.x;
    if (c == 0) { *gsumsq = 0.f; *ticket = 0u; }
    if (c >= NCODE) return;
    float v[64];
    const float4* src = (const float4*)(cb + (size_t)c * 64);
    float s = 0.f;
    #pragma unroll
    for (int i = 0; i < 16; i++) {
        float4 t = src[i];
        v[i*4+0] = t.x; v[i*4+1] = t.y; v[i*4+2] = t.z; v[i*4+3] = t.w;
        s += t.x*t.x + t.y*t.y + t.z*t.z + t.w*t.w;
    }
    cn4[c] = s + 4.0f;
    int cc = c >> 6, ct = (c >> 4) & 3, cl = c & 15;
    #pragma unroll
    for (int q = 0; q < 4; q++) {
        int half = q & 1, lo = q >> 1;
        #pragma unroll
        for (int g = 0; g < 4; g++) {
            unsigned short u8[8] __attribute__((aligned(16)));
            #pragma unroll
            for (int j = 0; j < 8; j++) {
                float f = v[half*32 + g*8 + j];
                unsigned short h = bf16_rne(f);
                if (lo) h = bf16_rne(f - __uint_as_float((unsigned)h << 16));
                u8[j] = h;
            }
            size_t off = (size_t)cc * 8192 + ct * 2048 + q * 512 + (g * 16 + cl) * 8;
            *(uint4*)(wsB + off) = *(const uint4*)u8;
        }
    }
}

// ---------------------------------------------------------------------------
// main: block = 64 rows x ALL 1024 codes; 4 waves x 16 rows. B double-buffered
// via global_load_lds(16B). Exact (d1,i1,d2) top-2 in regs; entropy via LDS
// atomicMin. NEW: ambiguous rows (gap<1.5e-4) fixed IN-BLOCK by a wave-0 fp64
// full scan BEFORE the emb gather -> tokens exact, sumsq exact, no global
// fixup pass, no amb/counter traffic.
// ---------------------------------------------------------------------------
__global__ __launch_bounds__(256, 4) void vq_main(
    const float* __restrict__ x, const float* __restrict__ cb,
    const unsigned short* __restrict__ wsB, const float* __restrict__ cn4,
    float* __restrict__ out, float* __restrict__ entPartial,
    float* __restrict__ gsumsq)
{
    __shared__ __align__(16) unsigned char Bb[2][16384];
    __shared__ float cn4L[2][64];
    __shared__ unsigned scrE[1024];   // per-block per-code min dist (raw f32 bits)
    __shared__ int   tokS[64];
    __shared__ float redS[4];
    __shared__ double xs64[64];
    __shared__ int   ambRows[AMB_MAX];
    __shared__ int   ambCnt;

    const int tid = threadIdx.x;
    const int lane = tid & 63;
    const int wi = tid >> 6;
    const int ln15 = lane & 15;
    const int q = lane >> 4;
    const int row0 = blockIdx.x * 64;
    const int wrow = row0 + wi * 16;

    // init scrE to +inf bits; zero amb count
    #pragma unroll
    for (int jj = 0; jj < 4; jj++) scrE[jj*256 + tid] = 0x7F800000u;
    if (tid == 0) ambCnt = 0;

    // preload chunk 0 (B + cn4) straight into LDS
    const char* wsBb = (const char*)wsB;
    {
        int wbase = (tid & ~63) * 16;   // wave-uniform part of (i*256+tid)*16
        #pragma unroll
        for (int i = 0; i < 4; i++)
            gl_lds16(wsBb + (i*256 + tid)*16, (void*)&Bb[0][i*4096 + wbase]);
        if (wi == 0) gl_lds4(cn4 + lane, (void*)&cn4L[0][0]);
    }

    // ---- A: 16 rows fp32 -> split-bf16 frags in regs; row norms via shfl ----
    bf16x8 Ah0, Ah1, Al0, Al1;
    float xnm4[4];
    {
        const float* xr = x + (size_t)(wrow + ln15) * 64 + q * 8;
        float4 f0 = *(const float4*)xr;
        float4 f1 = *(const float4*)(xr + 4);
        float4 f2 = *(const float4*)(xr + 32);
        float4 f3 = *(const float4*)(xr + 36);
        float fa[8] = {f0.x,f0.y,f0.z,f0.w,f1.x,f1.y,f1.z,f1.w};
        float fb[8] = {f2.x,f2.y,f2.z,f2.w,f3.x,f3.y,f3.z,f3.w};
        unsigned short h[8]  __attribute__((aligned(16)));
        unsigned short l[8]  __attribute__((aligned(16)));
        unsigned short h2[8] __attribute__((aligned(16)));
        unsigned short l2[8] __attribute__((aligned(16)));
        float ss = 0.f;
        #pragma unroll
        for (int j = 0; j < 8; j++) {
            ss += fa[j]*fa[j] + fb[j]*fb[j];
            unsigned short hh = bf16_rne(fa[j]);
            h[j] = hh; l[j] = bf16_rne(fa[j] - __uint_as_float((unsigned)hh << 16));
            hh = bf16_rne(fb[j]);
            h2[j] = hh; l2[j] = bf16_rne(fb[j] - __uint_as_float((unsigned)hh << 16));
        }
        Ah0 = *(const bf16x8*)h;  Al0 = *(const bf16x8*)l;
        Ah1 = *(const bf16x8*)h2; Al1 = *(const bf16x8*)l2;
        ss += __shfl_xor(ss, 16);
        ss += __shfl_xor(ss, 32);            // ||x_row(ln15)||^2
        #pragma unroll
        for (int r = 0; r < 4; r++)
            xnm4[r] = __shfl(ss, (q << 2) | r, 64) - 4.0f;  // xn(row q*4+r) - 4
    }

    float d1[4], d2[4];
    int   i1[4];
    #pragma unroll
    for (int r = 0; r < 4; r++) { d1[r] = INFINITY; d2[r] = INFINITY; i1[r] = 0; }

    // ---- chunk loop over all 1024 codes ----
    for (int cc = 0; cc < 16; cc++) {
        __syncthreads();   // drains prefetch: buf[cc&1]+cn4L[cc&1] ready; buf[nb] free
        const int cb_ = cc & 1, nb = (cc + 1) & 1;
        if (cc < 15) {
            int wbase = (tid & ~63) * 16;
            #pragma unroll
            for (int i = 0; i < 4; i++)
                gl_lds16(wsBb + (cc+1)*16384 + (i*256 + tid)*16,
                         (void*)&Bb[nb][i*4096 + wbase]);
            if (wi == 0) gl_lds4(cn4 + (cc+1)*64 + lane, (void*)&cn4L[nb][0]);
        }
        const unsigned char* buf = Bb[cb_];
        #pragma unroll
        for (int ct = 0; ct < 4; ct++) {
            bf16x8 Bh0 = *(const bf16x8*)(buf + ct*4096 +    0 + lane*16);
            bf16x8 Bh1 = *(const bf16x8*)(buf + ct*4096 + 1024 + lane*16);
            bf16x8 Bl0 = *(const bf16x8*)(buf + ct*4096 + 2048 + lane*16);
            bf16x8 Bl1 = *(const bf16x8*)(buf + ct*4096 + 3072 + lane*16);
            float cn4v = cn4L[cb_][ct*16 + ln15];
            int kid = cc*64 + ct*16 + ln15;
            f32x4 acc = {0.f, 0.f, 0.f, 0.f};
            acc = __builtin_amdgcn_mfma_f32_16x16x32_bf16(Ah0, Bh0, acc, 0, 0, 0);
            acc = __builtin_amdgcn_mfma_f32_16x16x32_bf16(Ah1, Bh1, acc, 0, 0, 0);
            acc = __builtin_amdgcn_mfma_f32_16x16x32_bf16(Ah0, Bl0, acc, 0, 0, 0);
            acc = __builtin_amdgcn_mfma_f32_16x16x32_bf16(Ah1, Bl1, acc, 0, 0, 0);
            acc = __builtin_amdgcn_mfma_f32_16x16x32_bf16(Al0, Bh0, acc, 0, 0, 0);
            acc = __builtin_amdgcn_mfma_f32_16x16x32_bf16(Al1, Bh1, acc, 0, 0, 0);
            float cminv = INFINITY;
            #pragma unroll
            for (int r = 0; r < 4; r++) {
                float wv = fmaf(acc[r], -2.0f, cn4v);   // 4 + cn - 2s  (>0)
                bool lt = wv < d1[r];
                d2[r] = lt ? d1[r] : fminf(d2[r], wv);
                i1[r] = lt ? kid   : i1[r];
                d1[r] = lt ? wv    : d1[r];
                cminv = fminf(cminv, wv + xnm4[r]);     // full dist (entropy)
            }
            cminv = fminf(cminv, __shfl_xor(cminv, 16));
            cminv = fminf(cminv, __shfl_xor(cminv, 32));
            if (q == ct) atomicMin(&scrE[kid], __float_as_uint(cminv));
        }
    }
    __syncthreads();   // scrE complete

    // ---- butterfly exact top-2 merge across the 16 code-column lanes ----
    #pragma unroll
    for (int d = 1; d < 16; d <<= 1) {
        #pragma unroll
        for (int r = 0; r < 4; r++) {
            float od1 = __shfl_xor(d1[r], d);
            int   oi1 = __shfl_xor(i1[r], d);
            float od2 = __shfl_xor(d2[r], d);
            bool take = (od1 < d1[r]) || (od1 == d1[r] && oi1 < i1[r]);
            float loser = take ? d1[r] : od1;
            d2[r] = fminf(fminf(d2[r], od2), loser);
            d1[r] = take ? od1 : d1[r];
            i1[r] = take ? oi1 : i1[r];
        }
    }
    if (ln15 == 0) {
        #pragma unroll
        for (int r = 0; r < 4; r++) {
            tokS[wi*16 + q*4 + r] = i1[r];
            if (d2[r] - d1[r] < GAP_THRESH) {
                int ii = atomicAdd(&ambCnt, 1);
                if (ii < AMB_MAX) ambRows[ii] = wi*16 + q*4 + r;
            }
        }
    }
    __syncthreads();   // tokS + ambRows ready

    // ---- in-block fp64 fixup (rare; wave 0 only, others wait at next sync) ----
    {
        int na = ambCnt; if (na > AMB_MAX) na = AMB_MAX;
        for (int a = 0; a < na; a++) {
            int row = ambRows[a];
            if (wi == 0) {
                double xd = (double)x[(size_t)(row0 + row)*64 + lane];
                xs64[lane] = xd;
                double xn = xd * xd;
                #pragma unroll
                for (int o = 1; o < 64; o <<= 1) xn += __shfl_xor(xn, o);
                double bd = INFINITY; int bk = 1 << 30;
                for (int j = 0; j < 16; j++) {
                    int k = j*64 + lane;
                    const float4* c4 = (const float4*)(cb + (size_t)k*64);
                    double dot = 0.0, cn2 = 0.0;
                    #pragma unroll 4
                    for (int t = 0; t < 16; t++) {
                        float4 cv = c4[t];
                        double cx = (double)cv.x, cy = (double)cv.y;
                        double cz = (double)cv.z, cw = (double)cv.w;
                        dot += xs64[t*4+0]*cx + xs64[t*4+1]*cy
                             + xs64[t*4+2]*cz + xs64[t*4+3]*cw;
                        cn2 += cx*cx + cy*cy + cz*cz + cw*cw;
                    }
                    double dist = (xn - 2.0*dot) + cn2;
                    if (dist < bd) { bd = dist; bk = k; }   // j ascending: first-index per lane
                }
                #pragma unroll
                for (int o = 1; o < 64; o <<= 1) {          // argmin w/ first-index tiebreak
                    double od = __shfl_xor(bd, o);
                    int    ok = __shfl_xor(bk, o);
                    if (od < bd || (od == bd && ok < bk)) { bd = od; bk = ok; }
                }
                if (lane == 0) tokS[row] = bk;
            }
        }
    }
    __syncthreads();   // corrected tokS visible to all

    // ---- entropy partials: coalesced per-block row ----
    #pragma unroll
    for (int jj = 0; jj < 4; jj++) {
        int c = jj*256 + tid;
        entPartial[(size_t)blockIdx.x * 1024 + c] = __uint_as_float(scrE[c]);
    }

    // ---- emb gather + sumsq (uses corrected tokens -> sumsq exact) ----
    {
        int grow = tid >> 2, p = tid & 3;
        int tok = tokS[grow];
        const float4* cv = (const float4*)(cb + (size_t)tok*64 + p*16);
        const float4* xv = (const float4*)(x  + (size_t)(row0 + grow)*64 + p*16);
        float4* ov = (float4*)(out + (size_t)(row0 + grow)*64 + p*16);
        float acc2 = 0.f;
        #pragma unroll
        for (int i = 0; i < 4; i++) {
            float4 c = cv[i]; float4 xx = xv[i];
            ov[i] = c;
            float dx = c.x-xx.x, dy = c.y-xx.y, dz = c.z-xx.z, dw = c.w-xx.w;
            acc2 += dx*dx + dy*dy + dz*dz + dw*dw;
        }
        #pragma unroll
        for (int o = 32; o > 0; o >>= 1) acc2 += __shfl_down(acc2, o);
        if ((tid & 63) == 0) redS[tid >> 6] = acc2;
        __syncthreads();
        if (tid == 0) atomicAdd(gsumsq, redS[0] + redS[1] + redS[2] + redS[3]);
    }
}

// ---------------------------------------------------------------------------
// tail: 256 blocks, NO fp64, NO x/cb reads. (A) coalesced 512->16 entropy
// row-reduction -> partial2. (B) last-ticket block: min over 16 + loss.
// ---------------------------------------------------------------------------
__global__ __launch_bounds__(256) void vq_tail(
    const float* __restrict__ entPartial, float* __restrict__ gsumsq,
    unsigned* __restrict__ ticket, float* __restrict__ partial2,
    float* __restrict__ out_loss)
{
    __shared__ float  scrR[256];
    __shared__ unsigned lastS;
    __shared__ float redS[4];

    const int tid = threadIdx.x;
    const int lane = tid & 63;
    const int wi = tid >> 6;

    // ---- A: coalesced 512->16 row-reduction of entPartial ----
    {
        int rg = blockIdx.x >> 4, cgp = blockIdx.x & 15;   // rows rg*32..+32, codes cgp*64..+64
        float m = INFINITY;
        #pragma unroll
        for (int r = 0; r < 8; r++)
            m = fminf(m, entPartial[(size_t)(rg*32 + wi*8 + r) * 1024 + cgp*64 + lane]);
        scrR[wi*64 + lane] = m;
        __syncthreads();
        if (wi == 0) {
            m = fminf(fminf(scrR[lane], scrR[64+lane]),
                      fminf(scrR[128+lane], scrR[192+lane]));
            partial2[(size_t)rg * 1024 + cgp*64 + lane] = m;
        }
    }

    // ---- B: last block assembles the loss ----
    __syncthreads();
    if (tid == 0) {
        __threadfence();
        lastS = (atomicAdd(ticket, 1u) == (unsigned)(gridDim.x - 1)) ? 1u : 0u;
    }
    __syncthreads();
    if (lastS) {
        __threadfence();
        volatile const float* p2 = partial2;
        float s = 0.f;
        #pragma unroll
        for (int jj = 0; jj < 4; jj++) {
            int c = jj*256 + tid;
            float mm = INFINITY;
            #pragma unroll
            for (int r = 0; r < 16; r++) mm = fminf(mm, p2[r*1024 + c]);
            s += mm;   // sum of per-code mins
        }
        #pragma unroll
        for (int o = 32; o > 0; o >>= 1) s += __shfl_down(s, o);
        if ((tid & 63) == 0) redS[tid >> 6] = s;
        __syncthreads();
        if (tid == 0) {
            volatile const float* gs = gsumsq;
            float tot = redS[0] + redS[1] + redS[2] + redS[3];
            out_loss[0] = 1.25f * (*gs / 2097152.0f) + 0.1f * (tot / 1024.0f);
        }
    }
}

extern "C" void kernel_launch(void* const* d_in, const int* in_sizes, int n_in,
                              void* d_out, int out_size, void* d_ws, size_t ws_size,
                              hipStream_t stream) {
    const float* x  = (const float*)d_in[0];   // [32768, 64]
    const float* cb = (const float*)d_in[1];   // [1024, 64]
    float* out = (float*)d_out;                // [0,2097152): emb; [2097152]: loss

    char* ws = (char*)d_ws;
    float*          gsumsq     = (float*)(ws + 4);                 // @4
    unsigned*       ticket     = (unsigned*)(ws + 8);              // @8
    float*          cn4        = (float*)(ws + 1024);              // 4 KB
    unsigned short* wsB        = (unsigned short*)(ws + 131072);   // 256 KB
    float*          partial2   = (float*)(ws + 393216);            // 64 KB
    float*          entPartial = (float*)(ws + 524288);            // 2 MB

    vq_prep<<<4,   256, 0, stream>>>(cb, cn4, gsumsq, ticket, wsB);
    vq_main<<<512, 256, 0, stream>>>(x, cb, wsB, cn4, out, entPartial, gsumsq);
    vq_tail<<<256, 256, 0, stream>>>(entPartial, gsumsq, ticket, partial2, out + 2097152);
}

// Round 8
// 136.177 us; speedup vs baseline: 1.1938x; 1.1938x over previous
//
#include <hip/hip_runtime.h>
#include <math.h>

#define NROWS 32768
#define NCODE 1024
#define AMB_CAP 8192
#define GAP_THRESH 1.5e-4f  // exact fp32 gap; emulation err ~1e-5, np-ref rounding ~2e-5

typedef __attribute__((ext_vector_type(8))) short bf16x8;   // 8 bf16 = 4 VGPRs
typedef __attribute__((ext_vector_type(4))) float f32x4;    // MFMA acc

__device__ __forceinline__ unsigned short bf16_rne(float f) {
    unsigned u = __float_as_uint(f);
    unsigned r = u + 0x7FFFu + ((u >> 16) & 1u);
    return (unsigned short)(r >> 16);
}

typedef const __attribute__((address_space(1))) unsigned GU;
typedef __attribute__((address_space(3))) unsigned LU;
__device__ __forceinline__ void gl_lds16(const void* g, void* l) {
    __builtin_amdgcn_global_load_lds((GU*)g, (LU*)l, 16, 0, 0);
}
__device__ __forceinline__ void gl_lds4(const void* g, void* l) {
    __builtin_amdgcn_global_load_lds((GU*)g, (LU*)l, 4, 0, 0);
}

// ---------------------------------------------------------------------------
// prep: cn4 = ||c||^2+4, minK=+inf bits, zero counter/gsumsq/ticket,
// codebook -> frag-major split-bf16 (wsB). chunk cc=c>>6 (16KB) | tile
// ct=(c>>4)&3 (4KB) | frag q {hi0-31,hi32-63,lo0-31,lo32-63} (1KB) | lane.
// ---------------------------------------------------------------------------
__global__ __launch_bounds__(256) void vq_prep(
    const float* __restrict__ cb, float* __restrict__ cn4,
    unsigned* __restrict__ minK, unsigned* __restrict__ counter,
    float* __restrict__ gsumsq, unsigned* __restrict__ ticket,
    unsigned short* __restrict__ wsB)
{
    int c = blockIdx.x * 256 + threadIdx.x;
    if (c == 0) { *counter = 0u; *gsumsq = 0.f; *ticket = 0u; }
    if (c >= NCODE) return;
    float v[64];
    const float4* src = (const float4*)(cb + (size_t)c * 64);
    float s = 0.f;
    #pragma unroll
    for (int i = 0; i < 16; i++) {
        float4 t = src[i];
        v[i*4+0] = t.x; v[i*4+1] = t.y; v[i*4+2] = t.z; v[i*4+3] = t.w;
        s += t.x*t.x + t.y*t.y + t.z*t.z + t.w*t.w;
    }
    cn4[c] = s + 4.0f;
    minK[c] = 0x7F800000u;   // +inf bits (all dists > 0 -> raw-bit order ok)
    int cc = c >> 6, ct = (c >> 4) & 3, cl = c & 15;
    #pragma unroll
    for (int q = 0; q < 4; q++) {
        int half = q & 1, lo = q >> 1;
        #pragma unroll
        for (int g = 0; g < 4; g++) {
            unsigned short u8[8] __attribute__((aligned(16)));
            #pragma unroll
            for (int j = 0; j < 8; j++) {
                float f = v[half*32 + g*8 + j];
                unsigned short h = bf16_rne(f);
                if (lo) h = bf16_rne(f - __uint_as_float((unsigned)h << 16));
                u8[j] = h;
            }
            size_t off = (size_t)cc * 8192 + ct * 2048 + q * 512 + (g * 16 + cl) * 8;
            *(uint4*)(wsB + off) = *(const uint4*)u8;
        }
    }
}

// ---------------------------------------------------------------------------
// main: block = 64 rows x ALL 1024 codes; 4 waves x 16 rows. B double-buffered
// via global_load_lds(16B). Chunk order ROTATED per block (rot=blockIdx&15)
// to decorrelate L2 bursts; ties caused by rotation have gap 0 -> fp64 fixup,
// so argmin semantics unchanged. Exact (d1,i1,d2) top-2 in regs; entropy via
// LDS atomicMin then filtered GLOBAL atomicMin(minK) (no entPartial pass).
// NO fp64 here (round-7 lesson: cold fp64 path starved hot-loop VGPRs 88->52).
// ---------------------------------------------------------------------------
__global__ __launch_bounds__(256, 4) void vq_main(
    const float* __restrict__ x, const float* __restrict__ cb,
    const unsigned short* __restrict__ wsB, const float* __restrict__ cn4,
    float* __restrict__ out, unsigned* __restrict__ minK,
    unsigned* __restrict__ counter, int* __restrict__ amb,
    float* __restrict__ gsumsq)
{
    __shared__ __align__(16) unsigned char Bb[2][16384];
    __shared__ float cn4L[2][64];
    __shared__ unsigned scrE[1024];   // per-block per-code min dist (raw f32 bits)
    __shared__ int   tokS[64];
    __shared__ float redS[4];

    const int tid = threadIdx.x;
    const int lane = tid & 63;
    const int wi = tid >> 6;
    const int ln15 = lane & 15;
    const int q = lane >> 4;
    const int row0 = blockIdx.x * 64;
    const int rot = blockIdx.x & 15;

    // init scrE to +inf bits
    #pragma unroll
    for (int jj = 0; jj < 4; jj++) scrE[jj*256 + tid] = 0x7F800000u;

    // preload physical chunk 'rot' (B + cn4) straight into LDS
    const char* wsBb = (const char*)wsB;
    {
        int wbase = (tid & ~63) * 16;   // wave-uniform part of (i*256+tid)*16
        #pragma unroll
        for (int i = 0; i < 4; i++)
            gl_lds16(wsBb + rot*16384 + (i*256 + tid)*16, (void*)&Bb[0][i*4096 + wbase]);
        if (wi == 0) gl_lds4(cn4 + rot*64 + lane, (void*)&cn4L[0][0]);
    }

    // ---- A: 16 rows fp32 -> split-bf16 frags in regs; row norms via shfl ----
    bf16x8 Ah0, Ah1, Al0, Al1;
    float xnm4[4];
    {
        const float* xr = x + (size_t)(row0 + wi*16 + ln15) * 64 + q * 8;
        float4 f0 = *(const float4*)xr;
        float4 f1 = *(const float4*)(xr + 4);
        float4 f2 = *(const float4*)(xr + 32);
        float4 f3 = *(const float4*)(xr + 36);
        float fa[8] = {f0.x,f0.y,f0.z,f0.w,f1.x,f1.y,f1.z,f1.w};
        float fb[8] = {f2.x,f2.y,f2.z,f2.w,f3.x,f3.y,f3.z,f3.w};
        unsigned short h[8]  __attribute__((aligned(16)));
        unsigned short l[8]  __attribute__((aligned(16)));
        unsigned short h2[8] __attribute__((aligned(16)));
        unsigned short l2[8] __attribute__((aligned(16)));
        float ss = 0.f;
        #pragma unroll
        for (int j = 0; j < 8; j++) {
            ss += fa[j]*fa[j] + fb[j]*fb[j];
            unsigned short hh = bf16_rne(fa[j]);
            h[j] = hh; l[j] = bf16_rne(fa[j] - __uint_as_float((unsigned)hh << 16));
            hh = bf16_rne(fb[j]);
            h2[j] = hh; l2[j] = bf16_rne(fb[j] - __uint_as_float((unsigned)hh << 16));
        }
        Ah0 = *(const bf16x8*)h;  Al0 = *(const bf16x8*)l;
        Ah1 = *(const bf16x8*)h2; Al1 = *(const bf16x8*)l2;
        ss += __shfl_xor(ss, 16);
        ss += __shfl_xor(ss, 32);            // ||x_row(ln15)||^2
        #pragma unroll
        for (int r = 0; r < 4; r++)
            xnm4[r] = __shfl(ss, (q << 2) | r, 64) - 4.0f;  // xn(row q*4+r) - 4
    }

    float d1[4], d2[4];
    int   i1[4];
    #pragma unroll
    for (int r = 0; r < 4; r++) { d1[r] = INFINITY; d2[r] = INFINITY; i1[r] = 0; }

    // ---- chunk loop over all 1024 codes (rotated order) ----
    for (int s = 0; s < 16; s++) {
        __syncthreads();   // drains prefetch: buf[s&1]+cn4L[s&1] ready; buf[nb] free
        const int cb_ = s & 1, nb = (s + 1) & 1;
        const int cphys = (s + rot) & 15;
        if (s < 15) {
            const int cnx = (s + 1 + rot) & 15;
            int wbase = (tid & ~63) * 16;
            #pragma unroll
            for (int i = 0; i < 4; i++)
                gl_lds16(wsBb + cnx*16384 + (i*256 + tid)*16,
                         (void*)&Bb[nb][i*4096 + wbase]);
            if (wi == 0) gl_lds4(cn4 + cnx*64 + lane, (void*)&cn4L[nb][0]);
        }
        const unsigned char* buf = Bb[cb_];
        #pragma unroll
        for (int ct = 0; ct < 4; ct++) {
            bf16x8 Bh0 = *(const bf16x8*)(buf + ct*4096 +    0 + lane*16);
            bf16x8 Bh1 = *(const bf16x8*)(buf + ct*4096 + 1024 + lane*16);
            bf16x8 Bl0 = *(const bf16x8*)(buf + ct*4096 + 2048 + lane*16);
            bf16x8 Bl1 = *(const bf16x8*)(buf + ct*4096 + 3072 + lane*16);
            float cn4v = cn4L[cb_][ct*16 + ln15];
            int kid = cphys*64 + ct*16 + ln15;
            f32x4 acc = {0.f, 0.f, 0.f, 0.f};
            acc = __builtin_amdgcn_mfma_f32_16x16x32_bf16(Ah0, Bh0, acc, 0, 0, 0);
            acc = __builtin_amdgcn_mfma_f32_16x16x32_bf16(Ah1, Bh1, acc, 0, 0, 0);
            acc = __builtin_amdgcn_mfma_f32_16x16x32_bf16(Ah0, Bl0, acc, 0, 0, 0);
            acc = __builtin_amdgcn_mfma_f32_16x16x32_bf16(Ah1, Bl1, acc, 0, 0, 0);
            acc = __builtin_amdgcn_mfma_f32_16x16x32_bf16(Al0, Bh0, acc, 0, 0, 0);
            acc = __builtin_amdgcn_mfma_f32_16x16x32_bf16(Al1, Bh1, acc, 0, 0, 0);
            float cminv = INFINITY;
            #pragma unroll
            for (int r = 0; r < 4; r++) {
                float wv = fmaf(acc[r], -2.0f, cn4v);   // 4 + cn - 2s  (>0)
                bool lt = wv < d1[r];
                d2[r] = lt ? d1[r] : fminf(d2[r], wv);
                i1[r] = lt ? kid   : i1[r];
                d1[r] = lt ? wv    : d1[r];
                cminv = fminf(cminv, wv + xnm4[r]);     // full dist (entropy)
            }
            cminv = fminf(cminv, __shfl_xor(cminv, 16));
            cminv = fminf(cminv, __shfl_xor(cminv, 32));
            if (q == ct) atomicMin(&scrE[kid], __float_as_uint(cminv));
        }
    }
    __syncthreads();   // scrE complete

    // ---- butterfly exact top-2 merge across the 16 code-column lanes ----
    #pragma unroll
    for (int d = 1; d < 16; d <<= 1) {
        #pragma unroll
        for (int r = 0; r < 4; r++) {
            float od1 = __shfl_xor(d1[r], d);
            int   oi1 = __shfl_xor(i1[r], d);
            float od2 = __shfl_xor(d2[r], d);
            bool take = (od1 < d1[r]) || (od1 == d1[r] && oi1 < i1[r]);
            float loser = take ? d1[r] : od1;
            d2[r] = fminf(fminf(d2[r], od2), loser);
            d1[r] = take ? od1 : d1[r];
            i1[r] = take ? oi1 : i1[r];
        }
    }
    if (ln15 == 0) {
        #pragma unroll
        for (int r = 0; r < 4; r++) {
            tokS[wi*16 + q*4 + r] = i1[r];
            if (d2[r] - d1[r] < GAP_THRESH) {
                unsigned idx = atomicAdd(counter, 1u);
                if (idx < AMB_CAP) {
                    amb[2*idx]   = row0 + wi*16 + q*4 + r;
                    amb[2*idx+1] = i1[r];
                }
            }
        }
    }
    __syncthreads();   // tokS ready

    // ---- entropy: filtered global atomicMin (replaces entPartial pass) ----
    #pragma unroll
    for (int jj = 0; jj < 4; jj++) {
        int c = jj*256 + tid;
        unsigned u = scrE[c];
        if (u < minK[c]) atomicMin(&minK[c], u);   // race benign: monotone
    }

    // ---- emb gather + sumsq ----
    {
        int grow = tid >> 2, p = tid & 3;
        int tok = tokS[grow];
        const float4* cv = (const float4*)(cb + (size_t)tok*64 + p*16);
        const float4* xv = (const float4*)(x  + (size_t)(row0 + grow)*64 + p*16);
        float4* ov = (float4*)(out + (size_t)(row0 + grow)*64 + p*16);
        float acc2 = 0.f;
        #pragma unroll
        for (int i = 0; i < 4; i++) {
            float4 c = cv[i]; float4 xx = xv[i];
            ov[i] = c;
            float dx = c.x-xx.x, dy = c.y-xx.y, dz = c.z-xx.z, dw = c.w-xx.w;
            acc2 += dx*dx + dy*dy + dz*dz + dw*dw;
        }
        #pragma unroll
        for (int o = 32; o > 0; o >>= 1) acc2 += __shfl_down(acc2, o);
        if ((tid & 63) == 0) redS[tid >> 6] = acc2;
        __syncthreads();
        if (tid == 0) atomicAdd(gsumsq, redS[0] + redS[1] + redS[2] + redS[3]);
    }
}

// ---------------------------------------------------------------------------
// tail: 64 blocks. (A) fp64 fixup of ambiguous rows (block-per-row).
// (B) last-ticket block: sum minK + loss. No entPartial, no big reads.
// ---------------------------------------------------------------------------
__global__ __launch_bounds__(256) void vq_tail(
    const float* __restrict__ x, const float* __restrict__ cb,
    float* __restrict__ out, const unsigned* __restrict__ counter,
    const int* __restrict__ amb, float* __restrict__ gsumsq,
    unsigned* __restrict__ ticket, const unsigned* __restrict__ minK,
    float* __restrict__ out_loss)
{
    __shared__ double xs[64];
    __shared__ double bd[256];
    __shared__ int    bi[256];
    __shared__ unsigned lastS;
    __shared__ float redS[4];

    const int tid = threadIdx.x;

    // ---- A: fp64 re-decision for ambiguous rows ----
    unsigned cnt = *counter; if (cnt > AMB_CAP) cnt = AMB_CAP;
    for (unsigned i = blockIdx.x; i < cnt; i += gridDim.x) {
        int row = amb[2*i], oldk = amb[2*i+1];
        __syncthreads();
        if (tid < 64) xs[tid] = (double)x[(size_t)row*64 + tid];
        __syncthreads();
        double xn = 0.0;
        #pragma unroll 8
        for (int d = 0; d < 64; d++) xn += xs[d]*xs[d];
        double best = INFINITY; int bk = 1 << 30;
        #pragma unroll
        for (int j = 0; j < 4; j++) {
            int k = j*256 + tid;
            const float4* c4 = (const float4*)(cb + (size_t)k*64);
            double dot = 0.0, cn2 = 0.0;
            #pragma unroll
            for (int t = 0; t < 16; t++) {
                float4 cv = c4[t];
                double cx = (double)cv.x, cy = (double)cv.y, cz = (double)cv.z, cw = (double)cv.w;
                dot += xs[t*4+0]*cx + xs[t*4+1]*cy + xs[t*4+2]*cz + xs[t*4+3]*cw;
                cn2 += cx*cx + cy*cy + cz*cz + cw*cw;
            }
            double dist = (xn - 2.0*dot) + cn2;
            if (dist < best || (dist == best && k < bk)) { best = dist; bk = k; }
        }
        bd[tid] = best; bi[tid] = bk;
        __syncthreads();
        for (int s = 128; s > 0; s >>= 1) {
            if (tid < s) {
                double od = bd[tid+s]; int ok = bi[tid+s];
                if (od < bd[tid] || (od == bd[tid] && ok < bi[tid])) { bd[tid] = od; bi[tid] = ok; }
            }
            __syncthreads();
        }
        int bestk = bi[0];
        if (bestk != oldk) {
            double part = 0.0;
            if (tid < 64) {
                float cn = cb[(size_t)bestk*64 + tid];
                float co = cb[(size_t)oldk*64 + tid];
                out[(size_t)row*64 + tid] = cn;
                double dn = (double)cn - xs[tid];
                double dl = (double)co - xs[tid];
                part = dn*dn - dl*dl;
            }
            __syncthreads();
            bd[tid] = part;
            __syncthreads();
            for (int s = 128; s > 0; s >>= 1) {
                if (tid < s) bd[tid] += bd[tid+s];
                __syncthreads();
            }
            if (tid == 0) atomicAdd(gsumsq, (float)bd[0]);
        }
    }

    // ---- B: last block assembles the loss ----
    __syncthreads();
    if (tid == 0) {
        __threadfence();
        lastS = (atomicAdd(ticket, 1u) == (unsigned)(gridDim.x - 1)) ? 1u : 0u;
    }
    __syncthreads();
    if (lastS) {
        __threadfence();
        float s = 0.f;
        #pragma unroll
        for (int jj = 0; jj < 4; jj++)
            s += __uint_as_float(minK[jj*256 + tid]);   // raw bits of positive dists
        #pragma unroll
        for (int o = 32; o > 0; o >>= 1) s += __shfl_down(s, o);
        if ((tid & 63) == 0) redS[tid >> 6] = s;
        __syncthreads();
        if (tid == 0) {
            float gs = atomicAdd(gsumsq, 0.0f);         // coherent device-scope read
            float tot = redS[0] + redS[1] + redS[2] + redS[3];
            out_loss[0] = 1.25f * (gs / 2097152.0f) + 0.1f * (tot / 1024.0f);
        }
    }
}

extern "C" void kernel_launch(void* const* d_in, const int* in_sizes, int n_in,
                              void* d_out, int out_size, void* d_ws, size_t ws_size,
                              hipStream_t stream) {
    const float* x  = (const float*)d_in[0];   // [32768, 64]
    const float* cb = (const float*)d_in[1];   // [1024, 64]
    float* out = (float*)d_out;                // [0,2097152): emb; [2097152]: loss

    char* ws = (char*)d_ws;
    unsigned*       counter = (unsigned*)ws;                    // @0
    float*          gsumsq  = (float*)(ws + 4);                 // @4
    unsigned*       ticket  = (unsigned*)(ws + 8);              // @8
    float*          cn4     = (float*)(ws + 1024);              // 4 KB
    unsigned*       minK    = (unsigned*)(ws + 8192);           // 4 KB
    int*            amb     = (int*)(ws + 16384);               // 64 KB
    unsigned short* wsB     = (unsigned short*)(ws + 131072);   // 256 KB

    vq_prep<<<4,   256, 0, stream>>>(cb, cn4, minK, counter, gsumsq, ticket, wsB);
    vq_main<<<512, 256, 0, stream>>>(x, cb, wsB, cn4, out, minK, counter, amb, gsumsq);
    vq_tail<<<64,  256, 0, stream>>>(x, cb, out, counter, amb, gsumsq, ticket, minK,
                                     out + 2097152);
}

// Round 9
// 130.566 us; speedup vs baseline: 1.2451x; 1.0430x over previous
//
#include <hip/hip_runtime.h>
#include <math.h>

#define NROWS 32768
#define NCODE 1024
#define AMB_CAP 8192
#define GAP_THRESH 1.5e-4f  // exact fp32 gap; emulation err ~1e-5, np-ref rounding ~2e-5

typedef __attribute__((ext_vector_type(8))) short bf16x8;   // 8 bf16 = 4 VGPRs
typedef __attribute__((ext_vector_type(4))) float f32x4;    // MFMA acc

__device__ __forceinline__ unsigned short bf16_rne(float f) {
    unsigned u = __float_as_uint(f);
    unsigned r = u + 0x7FFFu + ((u >> 16) & 1u);
    return (unsigned short)(r >> 16);
}

typedef const __attribute__((address_space(1))) unsigned GU;
typedef __attribute__((address_space(3))) unsigned LU;
__device__ __forceinline__ void gl_lds16(const void* g, void* l) {
    __builtin_amdgcn_global_load_lds((GU*)g, (LU*)l, 16, 0, 0);
}
__device__ __forceinline__ void gl_lds4(const void* g, void* l) {
    __builtin_amdgcn_global_load_lds((GU*)g, (LU*)l, 4, 0, 0);
}

// ---------------------------------------------------------------------------
// prep: cn4 = ||c||^2+4, minK=+inf bits, zero counter/gsumsq/ticket,
// codebook -> frag-major split-bf16 (wsB). 16 blocks x 64 codes.
// ---------------------------------------------------------------------------
__global__ __launch_bounds__(64) void vq_prep(
    const float* __restrict__ cb, float* __restrict__ cn4,
    unsigned* __restrict__ minK, unsigned* __restrict__ counter,
    float* __restrict__ gsumsq, unsigned* __restrict__ ticket,
    unsigned short* __restrict__ wsB)
{
    int c = blockIdx.x * 64 + threadIdx.x;
    if (c == 0) { *counter = 0u; *gsumsq = 0.f; *ticket = 0u; }
    float v[64];
    const float4* src = (const float4*)(cb + (size_t)c * 64);
    float s = 0.f;
    #pragma unroll
    for (int i = 0; i < 16; i++) {
        float4 t = src[i];
        v[i*4+0] = t.x; v[i*4+1] = t.y; v[i*4+2] = t.z; v[i*4+3] = t.w;
        s += t.x*t.x + t.y*t.y + t.z*t.z + t.w*t.w;
    }
    cn4[c] = s + 4.0f;
    minK[c] = 0x7F800000u;   // +inf bits (all dists > 0 -> raw-bit order ok)
    int cc = c >> 6, ct = (c >> 4) & 3, cl = c & 15;
    #pragma unroll
    for (int q = 0; q < 4; q++) {
        int half = q & 1, lo = q >> 1;
        #pragma unroll
        for (int g = 0; g < 4; g++) {
            unsigned short u8[8] __attribute__((aligned(16)));
            #pragma unroll
            for (int j = 0; j < 8; j++) {
                float f = v[half*32 + g*8 + j];
                unsigned short h = bf16_rne(f);
                if (lo) h = bf16_rne(f - __uint_as_float((unsigned)h << 16));
                u8[j] = h;
            }
            size_t off = (size_t)cc * 8192 + ct * 2048 + q * 512 + (g * 16 + cl) * 8;
            *(uint4*)(wsB + off) = *(const uint4*)u8;
        }
    }
}

// ---------------------------------------------------------------------------
// main: block = 64 rows x ALL 1024 codes, 512 threads (8 waves). Wave (g,h):
// rowGroup g = wi>>1 (16 rows), codeHalf h = wi&1 (2 of 4 ct tiles/chunk).
// -> 2 blocks/CU x 8 waves = 4 waves/SIMD (round-8 had 2: latency-bound at
// 68% idle). B double-buffered via global_load_lds(16B), chunk order rotated
// per block. Exact (d1,i1,d2) top-2 per half, exact LDS merge across halves.
// Entropy via LDS atomicMin then filtered global atomicMin. Emb fused.
// ---------------------------------------------------------------------------
__global__ __launch_bounds__(512, 4) void vq_main(
    const float* __restrict__ x, const float* __restrict__ cb,
    const unsigned short* __restrict__ wsB, const float* __restrict__ cn4,
    float* __restrict__ out, unsigned* __restrict__ minK,
    unsigned* __restrict__ counter, int* __restrict__ amb,
    float* __restrict__ gsumsq)
{
    __shared__ __align__(16) unsigned char Bb[2][16384];
    __shared__ float cn4L[2][64];
    __shared__ unsigned scrE[1024];   // per-block per-code min dist (raw f32 bits)
    __shared__ float mD1[128], mD2[128];   // per (row, half) top-2
    __shared__ int   mI1[128];
    __shared__ int   tokS[64];
    __shared__ float redS[8];

    const int tid = threadIdx.x;
    const int lane = tid & 63;
    const int wi = tid >> 6;         // 0..7
    const int g = wi >> 1;           // row group 0..3
    const int h = wi & 1;            // code half 0..1
    const int ln15 = lane & 15;
    const int q = lane >> 4;
    const int row0 = blockIdx.x * 64;
    const int rot = blockIdx.x & 15;

    // init scrE to +inf bits
    #pragma unroll
    for (int jj = 0; jj < 2; jj++) scrE[jj*512 + tid] = 0x7F800000u;

    // preload physical chunk 'rot' (B + cn4) straight into LDS
    const char* wsBb = (const char*)wsB;
    {
        int wbase = (tid & ~63) * 16;   // wave-uniform LDS base
        gl_lds16(wsBb + rot*16384 +        tid*16, (void*)&Bb[0][wbase]);
        gl_lds16(wsBb + rot*16384 + 8192 + tid*16, (void*)&Bb[0][8192 + wbase]);
        if (wi == 0) gl_lds4(cn4 + rot*64 + lane, (void*)&cn4L[0][0]);
    }

    // ---- A: 16 rows fp32 -> split-bf16 frags in regs; row norms via shfl ----
    bf16x8 Ah0, Ah1, Al0, Al1;
    float xnm4[4];
    {
        const float* xr = x + (size_t)(row0 + g*16 + ln15) * 64 + q * 8;
        float4 f0 = *(const float4*)xr;
        float4 f1 = *(const float4*)(xr + 4);
        float4 f2 = *(const float4*)(xr + 32);
        float4 f3 = *(const float4*)(xr + 36);
        float fa[8] = {f0.x,f0.y,f0.z,f0.w,f1.x,f1.y,f1.z,f1.w};
        float fb[8] = {f2.x,f2.y,f2.z,f2.w,f3.x,f3.y,f3.z,f3.w};
        unsigned short hh8[8] __attribute__((aligned(16)));
        unsigned short ll8[8] __attribute__((aligned(16)));
        unsigned short h28[8] __attribute__((aligned(16)));
        unsigned short l28[8] __attribute__((aligned(16)));
        float ss = 0.f;
        #pragma unroll
        for (int j = 0; j < 8; j++) {
            ss += fa[j]*fa[j] + fb[j]*fb[j];
            unsigned short hh = bf16_rne(fa[j]);
            hh8[j] = hh; ll8[j] = bf16_rne(fa[j] - __uint_as_float((unsigned)hh << 16));
            hh = bf16_rne(fb[j]);
            h28[j] = hh; l28[j] = bf16_rne(fb[j] - __uint_as_float((unsigned)hh << 16));
        }
        Ah0 = *(const bf16x8*)hh8; Al0 = *(const bf16x8*)ll8;
        Ah1 = *(const bf16x8*)h28; Al1 = *(const bf16x8*)l28;
        ss += __shfl_xor(ss, 16);
        ss += __shfl_xor(ss, 32);            // ||x_row(ln15)||^2
        #pragma unroll
        for (int r = 0; r < 4; r++)
            xnm4[r] = __shfl(ss, (q << 2) | r, 64) - 4.0f;  // xn(row q*4+r) - 4
    }

    float d1[4], d2[4];
    int   i1[4];
    #pragma unroll
    for (int r = 0; r < 4; r++) { d1[r] = INFINITY; d2[r] = INFINITY; i1[r] = 0; }

    // ---- chunk loop over all 1024 codes (rotated order) ----
    for (int s = 0; s < 16; s++) {
        __syncthreads();   // drains prefetch: buf[s&1]+cn4L[s&1] ready; buf[nb] free
        const int cb_ = s & 1, nb = (s + 1) & 1;
        const int cphys = (s + rot) & 15;
        if (s < 15) {
            const int cnx = (s + 1 + rot) & 15;
            int wbase = (tid & ~63) * 16;
            gl_lds16(wsBb + cnx*16384 +        tid*16, (void*)&Bb[nb][wbase]);
            gl_lds16(wsBb + cnx*16384 + 8192 + tid*16, (void*)&Bb[nb][8192 + wbase]);
            if (wi == 0) gl_lds4(cn4 + cnx*64 + lane, (void*)&cn4L[nb][0]);
        }
        const unsigned char* buf = Bb[cb_];
        #pragma unroll
        for (int lct = 0; lct < 2; lct++) {
            const int ct = 2*h + lct;
            bf16x8 Bh0 = *(const bf16x8*)(buf + ct*4096 +    0 + lane*16);
            bf16x8 Bh1 = *(const bf16x8*)(buf + ct*4096 + 1024 + lane*16);
            bf16x8 Bl0 = *(const bf16x8*)(buf + ct*4096 + 2048 + lane*16);
            bf16x8 Bl1 = *(const bf16x8*)(buf + ct*4096 + 3072 + lane*16);
            float cn4v = cn4L[cb_][ct*16 + ln15];
            int kid = cphys*64 + ct*16 + ln15;
            f32x4 acc = {0.f, 0.f, 0.f, 0.f};
            acc = __builtin_amdgcn_mfma_f32_16x16x32_bf16(Ah0, Bh0, acc, 0, 0, 0);
            acc = __builtin_amdgcn_mfma_f32_16x16x32_bf16(Ah1, Bh1, acc, 0, 0, 0);
            acc = __builtin_amdgcn_mfma_f32_16x16x32_bf16(Ah0, Bl0, acc, 0, 0, 0);
            acc = __builtin_amdgcn_mfma_f32_16x16x32_bf16(Ah1, Bl1, acc, 0, 0, 0);
            acc = __builtin_amdgcn_mfma_f32_16x16x32_bf16(Al0, Bh0, acc, 0, 0, 0);
            acc = __builtin_amdgcn_mfma_f32_16x16x32_bf16(Al1, Bh1, acc, 0, 0, 0);
            float cminv = INFINITY;
            #pragma unroll
            for (int r = 0; r < 4; r++) {
                float wv = fmaf(acc[r], -2.0f, cn4v);   // 4 + cn - 2s  (>0)
                bool lt = wv < d1[r];
                d2[r] = lt ? d1[r] : fminf(d2[r], wv);
                i1[r] = lt ? kid   : i1[r];
                d1[r] = lt ? wv    : d1[r];
                cminv = fminf(cminv, wv + xnm4[r]);     // full dist (entropy)
            }
            cminv = fminf(cminv, __shfl_xor(cminv, 16));
            cminv = fminf(cminv, __shfl_xor(cminv, 32));
            if (q == lct) atomicMin(&scrE[kid], __float_as_uint(cminv));
        }
    }
    __syncthreads();   // scrE complete; all compute done

    // ---- butterfly exact top-2 merge across the 16 code-column lanes ----
    #pragma unroll
    for (int d = 1; d < 16; d <<= 1) {
        #pragma unroll
        for (int r = 0; r < 4; r++) {
            float od1 = __shfl_xor(d1[r], d);
            int   oi1 = __shfl_xor(i1[r], d);
            float od2 = __shfl_xor(d2[r], d);
            bool take = (od1 < d1[r]) || (od1 == d1[r] && oi1 < i1[r]);
            float loser = take ? d1[r] : od1;
            d2[r] = fminf(fminf(d2[r], od2), loser);
            d1[r] = take ? od1 : d1[r];
            i1[r] = take ? oi1 : i1[r];
        }
    }
    if (ln15 == 0) {
        #pragma unroll
        for (int r = 0; r < 4; r++) {
            int idx = (g*16 + q*4 + r) * 2 + h;
            mD1[idx] = d1[r]; mI1[idx] = i1[r]; mD2[idx] = d2[r];
        }
    }
    __syncthreads();   // per-half candidates staged

    // ---- exact cross-half merge -> token + ambiguity (one thread per row) ----
    if (tid < 64) {
        float a1 = mD1[tid*2],   b1 = mD1[tid*2+1];
        int   ai = mI1[tid*2],   bi = mI1[tid*2+1];
        float a2 = mD2[tid*2],   b2 = mD2[tid*2+1];
        bool ta = (a1 < b1) || (a1 == b1 && ai < bi);
        float D1 = ta ? a1 : b1;
        int   I1 = ta ? ai : bi;
        float D2 = ta ? fminf(a2, b1) : fminf(b2, a1);
        tokS[tid] = I1;
        if (D2 - D1 < GAP_THRESH) {
            unsigned idx = atomicAdd(counter, 1u);
            if (idx < AMB_CAP) { amb[2*idx] = row0 + tid; amb[2*idx+1] = I1; }
        }
    }

    // ---- entropy: filtered global atomicMin ----
    #pragma unroll
    for (int jj = 0; jj < 2; jj++) {
        int c = jj*512 + tid;
        unsigned u = scrE[c];
        if (u < minK[c]) atomicMin(&minK[c], u);   // race benign: monotone
    }
    __syncthreads();   // tokS ready

    // ---- emb gather + sumsq (512 threads x 2 float4 units) ----
    {
        float acc2 = 0.f;
        #pragma unroll
        for (int uu = 0; uu < 2; uu++) {
            int u = uu*512 + tid;
            int row = u >> 4, c4 = u & 15;
            int tok = tokS[row];
            float4 c = ((const float4*)(cb + (size_t)tok*64))[c4];
            float4 xx = ((const float4*)(x + (size_t)(row0 + row)*64))[c4];
            ((float4*)(out + (size_t)(row0 + row)*64))[c4] = c;
            float dx = c.x-xx.x, dy = c.y-xx.y, dz = c.z-xx.z, dw = c.w-xx.w;
            acc2 += dx*dx + dy*dy + dz*dz + dw*dw;
        }
        #pragma unroll
        for (int o = 32; o > 0; o >>= 1) acc2 += __shfl_down(acc2, o);
        if (lane == 0) redS[wi] = acc2;
        __syncthreads();
        if (tid == 0) {
            float t = 0.f;
            #pragma unroll
            for (int w = 0; w < 8; w++) t += redS[w];
            atomicAdd(gsumsq, t);
        }
    }
}

// ---------------------------------------------------------------------------
// tail: 64 blocks. (A) fp64 fixup of ambiguous rows (block-per-row).
// (B) last-ticket block: sum minK + loss.
// ---------------------------------------------------------------------------
__global__ __launch_bounds__(256) void vq_tail(
    const float* __restrict__ x, const float* __restrict__ cb,
    float* __restrict__ out, const unsigned* __restrict__ counter,
    const int* __restrict__ amb, float* __restrict__ gsumsq,
    unsigned* __restrict__ ticket, const unsigned* __restrict__ minK,
    float* __restrict__ out_loss)
{
    __shared__ double xs[64];
    __shared__ double bd[256];
    __shared__ int    bi[256];
    __shared__ unsigned lastS;
    __shared__ float redS[4];

    const int tid = threadIdx.x;

    // ---- A: fp64 re-decision for ambiguous rows ----
    unsigned cnt = *counter; if (cnt > AMB_CAP) cnt = AMB_CAP;
    for (unsigned i = blockIdx.x; i < cnt; i += gridDim.x) {
        int row = amb[2*i], oldk = amb[2*i+1];
        __syncthreads();
        if (tid < 64) xs[tid] = (double)x[(size_t)row*64 + tid];
        __syncthreads();
        double xn = 0.0;
        #pragma unroll 8
        for (int d = 0; d < 64; d++) xn += xs[d]*xs[d];
        double best = INFINITY; int bk = 1 << 30;
        #pragma unroll
        for (int j = 0; j < 4; j++) {
            int k = j*256 + tid;
            const float4* c4 = (const float4*)(cb + (size_t)k*64);
            double dot = 0.0, cn2 = 0.0;
            #pragma unroll
            for (int t = 0; t < 16; t++) {
                float4 cv = c4[t];
                double cx = (double)cv.x, cy = (double)cv.y, cz = (double)cv.z, cw = (double)cv.w;
                dot += xs[t*4+0]*cx + xs[t*4+1]*cy + xs[t*4+2]*cz + xs[t*4+3]*cw;
                cn2 += cx*cx + cy*cy + cz*cz + cw*cw;
            }
            double dist = (xn - 2.0*dot) + cn2;
            if (dist < best || (dist == best && k < bk)) { best = dist; bk = k; }
        }
        bd[tid] = best; bi[tid] = bk;
        __syncthreads();
        for (int s = 128; s > 0; s >>= 1) {
            if (tid < s) {
                double od = bd[tid+s]; int ok = bi[tid+s];
                if (od < bd[tid] || (od == bd[tid] && ok < bi[tid])) { bd[tid] = od; bi[tid] = ok; }
            }
            __syncthreads();
        }
        int bestk = bi[0];
        if (bestk != oldk) {
            double part = 0.0;
            if (tid < 64) {
                float cn = cb[(size_t)bestk*64 + tid];
                float co = cb[(size_t)oldk*64 + tid];
                out[(size_t)row*64 + tid] = cn;
                double dn = (double)cn - xs[tid];
                double dl = (double)co - xs[tid];
                part = dn*dn - dl*dl;
            }
            __syncthreads();
            bd[tid] = part;
            __syncthreads();
            for (int s = 128; s > 0; s >>= 1) {
                if (tid < s) bd[tid] += bd[tid+s];
                __syncthreads();
            }
            if (tid == 0) atomicAdd(gsumsq, (float)bd[0]);
        }
    }

    // ---- B: last block assembles the loss ----
    __syncthreads();
    if (tid == 0) {
        __threadfence();
        lastS = (atomicAdd(ticket, 1u) == (unsigned)(gridDim.x - 1)) ? 1u : 0u;
    }
    __syncthreads();
    if (lastS) {
        __threadfence();
        float s = 0.f;
        #pragma unroll
        for (int jj = 0; jj < 4; jj++)
            s += __uint_as_float(minK[jj*256 + tid]);   // raw bits of positive dists
        #pragma unroll
        for (int o = 32; o > 0; o >>= 1) s += __shfl_down(s, o);
        if ((tid & 63) == 0) redS[tid >> 6] = s;
        __syncthreads();
        if (tid == 0) {
            float gs = atomicAdd(gsumsq, 0.0f);         // coherent device-scope read
            float tot = redS[0] + redS[1] + redS[2] + redS[3];
            out_loss[0] = 1.25f * (gs / 2097152.0f) + 0.1f * (tot / 1024.0f);
        }
    }
}

extern "C" void kernel_launch(void* const* d_in, const int* in_sizes, int n_in,
                              void* d_out, int out_size, void* d_ws, size_t ws_size,
                              hipStream_t stream) {
    const float* x  = (const float*)d_in[0];   // [32768, 64]
    const float* cb = (const float*)d_in[1];   // [1024, 64]
    float* out = (float*)d_out;                // [0,2097152): emb; [2097152]: loss

    char* ws = (char*)d_ws;
    unsigned*       counter = (unsigned*)ws;                    // @0
    float*          gsumsq  = (float*)(ws + 4);                 // @4
    unsigned*       ticket  = (unsigned*)(ws + 8);              // @8
    float*          cn4     = (float*)(ws + 1024);              // 4 KB
    unsigned*       minK    = (unsigned*)(ws + 8192);           // 4 KB
    int*            amb     = (int*)(ws + 16384);               // 64 KB
    unsigned short* wsB     = (unsigned short*)(ws + 131072);   // 256 KB

    vq_prep<<<16,  64,  0, stream>>>(cb, cn4, minK, counter, gsumsq, ticket, wsB);
    vq_main<<<512, 512, 0, stream>>>(x, cb, wsB, cn4, out, minK, counter, amb, gsumsq);
    vq_tail<<<64,  256, 0, stream>>>(x, cb, out, counter, amb, gsumsq, ticket, minK,
                                     out + 2097152);
}